// Round 23
// baseline (38.919 us; speedup 1.0000x reference)
//
#include <hip/hip_runtime.h>
#include <hip/hip_bf16.h>

#define T_LEN   2000
#define NKER    256
#define LPAD    128          // padded l-dim (Lmax <= 127)
#define NE      2128         // shifted entries staged (>= T_LEN + Lmax - 1)
#define THREADS 512

typedef int   v4i __attribute__((ext_vector_type(4)));
typedef float v4f __attribute__((ext_vector_type(4)));

// raw-asm MFMA. "=&v" early-clobber: D must not alias A/B (multi-pass XDL);
// R7's absmax=4.3 failure was the allocator aliasing D with a dying B input.
__device__ inline v4f mfma_z(v4i a, v4i b, v4f c) {
    v4f d;
    asm volatile("v_mfma_f32_16x16x32_bf16 %0, %1, %2, %3"
                 : "=&v"(d) : "v"(a), "v"(b), "v"(c));
    return d;
}
__device__ inline void mfma_acc(v4f& acc, v4i a, v4i b) {
    asm volatile("v_mfma_f32_16x16x32_bf16 %0, %1, %2, %0"
                 : "+v"(acc) : "v"(a), "v"(b));
}
// chain-final MFMA: s_nop covers MFMA->VALU RAW hazard (opaque to compiler)
__device__ inline void mfma_acc_last(v4f& acc, v4i a, v4i b) {
    asm volatile("v_mfma_f32_16x16x32_bf16 %0, %1, %2, %0\n\ts_nop 7"
                 : "+v"(acc) : "v"(a), "v"(b));
}

// minimal 3-op epilogue: cmp into vcc, carry-accumulate count, running max.
// (compiler tends to emit cmp+cndmask+add+max plus movs = 4-6 ops)
__device__ inline void epi1(unsigned& cnt, float& mx, float acc, float nb) {
    asm volatile("v_cmp_gt_f32 vcc, %2, %3\n\t"
                 "v_addc_co_u32 %0, vcc, 0, %0, vcc\n\t"
                 "v_max_f32 %1, %1, %2"
                 : "+v"(cnt), "+v"(mx)
                 : "v"(acc), "v"(nb)
                 : "vcc");
}

__device__ inline unsigned f2bf(float f) {
    return (unsigned)__builtin_bit_cast(unsigned short, __float2bfloat16(f));
}

// ---------------------------------------------------------------------------
// Prep: dense bf16 weight bank [256][128], zero-padded (bias folded into
// epilogue: cnt uses acc > -b, max gets +b at final write).
// ---------------------------------------------------------------------------
__global__ void rocket_prep(const float* __restrict__ W, int Lmax,
                            unsigned* __restrict__ Wbf32) {
    const int k = blockIdx.x;
    const int t = threadIdx.x;           // 0..63
    const int l0 = 2 * t, l1 = 2 * t + 1;
    float v0 = (l0 < Lmax) ? W[k * Lmax + l0] : 0.0f;
    float v1 = (l1 < Lmax) ? W[k * Lmax + l1] : 0.0f;
    Wbf32[k * (LPAD / 2) + t] = f2bf(v0) | (f2bf(v1) << 16);
}

// ---------------------------------------------------------------------------
// Main (R9 champion structure, verbatim except asm epilogue):
// grid (256 bc, 4 sub) x 512 threads (8 waves = 2 kp x 4 tq).
// Wave: 2 ktiles (32 kernels) x 32/29 t-tiles (split 32/32/32/29).
// 8-slot sliding register window: B-entry (tile tau, slot s) is J = tau+2s
// at LDS byte 288*J + voff; w[J%8] gives 1 ds_read_b128/tile steady-state,
// all-literal slot indices.
// ---------------------------------------------------------------------------
__global__ __launch_bounds__(THREADS, 4) void rocket_main(
    const float* __restrict__ x, const float* __restrict__ bias,
    const unsigned short* __restrict__ Wbf, float* __restrict__ out,
    int Lmax) {

    __shared__ __align__(16) uint4 sx8[2400];     // idx max 2392
    __shared__ unsigned pc[64][4];
    __shared__ float    pm[64][4];

    const int bc  = blockIdx.x;
    const int sub = blockIdx.y;          // kernel group of 64
    const int tid = threadIdx.x;
    const int c0  = (Lmax - 1) >> 1;

    // ---- stage shifted entries: 5 consecutive entries per thread ----
    {
        const int base = tid * 5;
        if (base < NE) {
            float xv[12];
            #pragma unroll
            for (int i = 0; i < 12; ++i) {
                int s = base + i - c0;
                xv[i] = (s >= 0 && s < T_LEN) ? x[bc * T_LEN + s] : 0.0f;
            }
            unsigned hb[12];
            #pragma unroll
            for (int i = 0; i < 12; ++i) hb[i] = f2bf(xv[i]);
            #pragma unroll
            for (int i = 0; i < 5; ++i) {
                int p = base + i;
                if (p < NE) {
                    uint4 v;
                    v.x = hb[i]     | (hb[i + 1] << 16);
                    v.y = hb[i + 2] | (hb[i + 3] << 16);
                    v.z = hb[i + 4] | (hb[i + 5] << 16);
                    v.w = hb[i + 6] | (hb[i + 7] << 16);
                    sx8[p + (p >> 3)] = v;
                }
            }
        }
    }

    const int lane = tid & 63;
    const int wid  = tid >> 6;
    const int kp   = wid >> 2;       // 0..1: local ktile-pair
    const int tq   = wid & 3;        // t quarter
    const int g    = lane >> 4;
    const int c    = lane & 15;

    // ---- A fragments: 2 ktiles x 4 k-steps in registers (32 VGPR) ----
    v4i afrag[2][4];
    #pragma unroll
    for (int kt = 0; kt < 2; ++kt) {
        #pragma unroll
        for (int s = 0; s < 4; ++s) {
            const unsigned short* src =
                Wbf + ((sub * 4 + kp * 2 + kt) * 16 + c) * LPAD + s * 32 + g * 8;
            afrag[kt][s] = *reinterpret_cast<const v4i*>(src);
        }
    }

    // ---- negated bias per owned row: nb[kt][r] for rows g*4+r ----
    float nb[2][4];
    #pragma unroll
    for (int kt = 0; kt < 2; ++kt) {
        float4 bv = *reinterpret_cast<const float4*>(
            bias + sub * 64 + (kp * 2 + kt) * 16 + g * 4);
        nb[kt][0] = -bv.x; nb[kt][1] = -bv.y;
        nb[kt][2] = -bv.z; nb[kt][3] = -bv.w;
    }

    __syncthreads();

    unsigned cnt[2][4] = {};
    float    mx[2][4];
    #pragma unroll
    for (int kt = 0; kt < 2; ++kt)
        #pragma unroll
        for (int r = 0; r < 4; ++r) mx[kt][r] = -__builtin_inff();

    v4f zero4 = {0.f, 0.f, 0.f, 0.f};
    asm("" : "+v"(zero4));   // pin: persistent zero C-quad

    const int pb = g * 8 + c;                        // 0..39
    const unsigned voff = (unsigned)(pb + (pb >> 3)) << 4;

    // per-tile compute: 2 chains of 4 MFMA + 3-op asm epilogue per element
    auto do_tile = [&](v4i b0, v4i b1, v4i b2, v4i b3) {
        #pragma unroll
        for (int kt = 0; kt < 2; ++kt) {
            v4f acc = mfma_z(afrag[kt][0], b0, zero4);
            mfma_acc(acc, afrag[kt][1], b1);
            mfma_acc(acc, afrag[kt][2], b2);
            mfma_acc_last(acc, afrag[kt][3], b3);
            #pragma unroll
            for (int r = 0; r < 4; ++r)
                epi1(cnt[kt][r], mx[kt][r], acc[r], nb[kt][r]);
        }
    };

    const int tstart = tq * 32;                      // 32/32/32/29 split
    const int nms    = (tq == 3) ? 3 : 4;            // 8-tile macro-steps

    // entry J lives at byte 288*J + voff (idx = 18J + pb + (pb>>3))
    const char* p = (const char*)sx8 + voff + 288u * (unsigned)tstart;

    // ---- window prologue: J = tstart..tstart+7 in slots 0..7 ----
    v4i w[8];
    #pragma unroll
    for (int j = 0; j < 8; ++j)
        w[j] = *reinterpret_cast<const v4i*>(p + 288 * j);

    #pragma unroll 1
    for (int ms = 0; ms < nms; ++ms) {
        #pragma unroll
        for (int m = 0; m < 4; ++m) {
            // tile 2m: slots (2m+2s)&7
            do_tile(w[(2*m + 0) & 7], w[(2*m + 2) & 7],
                    w[(2*m + 4) & 7], w[(2*m + 6) & 7]);
            // tile 2m+1: slots (2m+1+2s)&7
            do_tile(w[(2*m + 1) & 7], w[(2*m + 3) & 7],
                    w[(2*m + 5) & 7], w[(2*m + 7) & 7]);
            // slide: J+8, J+9 into freed slots
            w[(2*m + 0) & 7] = *reinterpret_cast<const v4i*>(p + 288 * (2*m + 8));
            w[(2*m + 1) & 7] = *reinterpret_cast<const v4i*>(p + 288 * (2*m + 9));
        }
        p += 2304;                                   // 8 tiles * 288
    }

    if (tq == 3) {
        // tail tiles 120..124 (rel 0..4 from p): plain 4-read path
        #pragma unroll
        for (int tt = 0; tt < 5; ++tt) {
            v4i b0 = *reinterpret_cast<const v4i*>(p + 288 * (tt + 0));
            v4i b1 = *reinterpret_cast<const v4i*>(p + 288 * (tt + 2));
            v4i b2 = *reinterpret_cast<const v4i*>(p + 288 * (tt + 4));
            v4i b3 = *reinterpret_cast<const v4i*>(p + 288 * (tt + 6));
            do_tile(b0, b1, b2, b3);
        }
    }

    // ---- col reduce over 16 lanes via DPP row_ror (no LDS pipe) ----
    #pragma unroll
    for (int kt = 0; kt < 2; ++kt) {
        #pragma unroll
        for (int r = 0; r < 4; ++r) {
            unsigned cv = cnt[kt][r];
            cv += (unsigned)__builtin_amdgcn_update_dpp(0, (int)cv, 0x128, 0xF, 0xF, true);
            cv += (unsigned)__builtin_amdgcn_update_dpp(0, (int)cv, 0x124, 0xF, 0xF, true);
            cv += (unsigned)__builtin_amdgcn_update_dpp(0, (int)cv, 0x122, 0xF, 0xF, true);
            cv += (unsigned)__builtin_amdgcn_update_dpp(0, (int)cv, 0x121, 0xF, 0xF, true);
            float mv = mx[kt][r];
            mv = fmaxf(mv, __builtin_bit_cast(float,
                 __builtin_amdgcn_update_dpp(0, __builtin_bit_cast(int, mv), 0x128, 0xF, 0xF, true)));
            mv = fmaxf(mv, __builtin_bit_cast(float,
                 __builtin_amdgcn_update_dpp(0, __builtin_bit_cast(int, mv), 0x124, 0xF, 0xF, true)));
            mv = fmaxf(mv, __builtin_bit_cast(float,
                 __builtin_amdgcn_update_dpp(0, __builtin_bit_cast(int, mv), 0x122, 0xF, 0xF, true)));
            mv = fmaxf(mv, __builtin_bit_cast(float,
                 __builtin_amdgcn_update_dpp(0, __builtin_bit_cast(int, mv), 0x121, 0xF, 0xF, true)));
            if (c == 0) {
                const int klo = (kp * 2 + kt) * 16 + g * 4 + r;   // 0..63
                pc[klo][tq] = cv;
                pm[klo][tq] = mv;
            }
        }
    }
    __syncthreads();

    if (tid < 64) {
        unsigned ct = pc[tid][0] + pc[tid][1] + pc[tid][2] + pc[tid][3];
        float mv = fmaxf(fmaxf(pm[tid][0], pm[tid][1]),
                         fmaxf(pm[tid][2], pm[tid][3]));
        const int kk = sub * 64 + tid;
        out[bc * (2 * NKER) + 2 * kk]     = (float)ct * (1.0f / T_LEN);
        out[bc * (2 * NKER) + 2 * kk + 1] = mv + bias[kk];   // bias folded here
    }
}

extern "C" void kernel_launch(void* const* d_in, const int* in_sizes, int n_in,
                              void* d_out, int out_size, void* d_ws, size_t ws_size,
                              hipStream_t stream) {
    const float* x    = (const float*)d_in[0];
    const float* W    = (const float*)d_in[1];
    const float* bias = (const float*)d_in[2];
    float*       out  = (float*)d_out;

    const int Lmax = in_sizes[1] / NKER;

    unsigned* Wbf32 = (unsigned*)d_ws;             // 256*128*2 = 64 KB

    rocket_prep<<<dim3(NKER), dim3(64), 0, stream>>>(W, Lmax, Wbf32);
    rocket_main<<<dim3(256, 4), dim3(THREADS), 0, stream>>>(
        x, bias, (const unsigned short*)Wbf32, out, Lmax);
}